// Round 4
// baseline (193.320 us; speedup 1.0000x reference)
//
#include <hip/hip_runtime.h>

// CPRPackedLinear: out(64x11008) = xperm[:, :1024] @ deq6(W_high) + xperm[:, 1024:] @ deq5(W_low) + bias
//
// R4: barrier-free rewrite. R1-R3 proved the 8-wave barrier-lockstep LDS-staging
// structure is the bottleneck (3 different schedules, identical 51-54us, all pipes
// <20%): the per-tile s_barrier broadcasts the worst wave's load miss to the whole
// block. Key realization: the 16x16x32 B-fragment is "lane holds 8 CONSECUTIVE k
// at one column" -- exactly what one thread's 6-bit/5-bit dequant produces. So
// dequant directly into the MFMA B operand in registers: no LDS, no barriers.
// Each wave independently owns 16 cols x 64 rows x 512-k chunk; latency is hidden
// by TLP (21.5 waves/CU) + unconstrained compiler pipelining.

#define NFEAT 11008
#define KTOT  4096

typedef _Float16 half8 __attribute__((ext_vector_type(8)));
typedef float    f32x4 __attribute__((ext_vector_type(4)));

// ---------------- prep: x_perm -> fp16 in MFMA A-fragment layout ----------------
// xfrag flat idx = ((s*4 + mt)*64 + lane)*8 + j
//   holds x[m = mt*16 + (lane&15)][ col_indices[k = s*32 + (lane>>4)*8 + j] ]
__global__ __launch_bounds__(256) void prep_xfrag(const float* __restrict__ x,
                                                  const int* __restrict__ col,
                                                  _Float16* __restrict__ xfrag) {
    int idx = blockIdx.x * 256 + threadIdx.x;          // 0..262143
    int j  = idx & 7;
    int l  = (idx >> 3) & 63;
    int mt = (idx >> 9) & 3;
    int s  = idx >> 11;
    int k  = s * 32 + ((l >> 4) << 3) + j;
    int m  = mt * 16 + (l & 15);
    xfrag[idx] = (_Float16)x[m * KTOT + col[k]];
}

// ---------------- main GEMM (barrier-free, wave-independent) ----------------
// grid.x = 172 (64-col block tiles), grid.y = #k-chunks (8 preferred, 4 fallback).
// block = 256 = 4 waves; wave w owns cols [n0 + 16w, n0 + 16w + 16), all 64 rows,
// k-chunk [kc*klen, (kc+1)*klen). Chunks never straddle the 6bit/5bit boundary
// (1024 is a multiple of klen).
__global__ __launch_bounds__(256, 4) void gemm_kernel(const int* __restrict__ Wh,
                                                      const int* __restrict__ Wl,
                                                      const float* __restrict__ sh,
                                                      const float* __restrict__ sl,
                                                      const _Float16* __restrict__ xfrag,
                                                      float* __restrict__ dst,
                                                      int atomic_mode) {
    const int n0   = blockIdx.x * 64;
    const int kc   = blockIdx.y;
    const int klen = KTOT / gridDim.y;                  // 512 or 1024
    const int k0   = kc * klen;
    const int lane = threadIdx.x & 63;
    const int wave = threadIdx.x >> 6;                  // 0..3

    const int n  = n0 + wave * 16 + (lane & 15);        // this lane's output column
    const int kb = (lane >> 4) << 3;                    // lane's k-block within a 32-k step

    f32x4 acc[4];
#pragma unroll
    for (int i = 0; i < 4; ++i) acc[i] = (f32x4){0.f, 0.f, 0.f, 0.f};

    const int ngroups = klen >> 7;                      // 128-k scale groups per chunk

    if (k0 < 1024) {
        // ================= 6-bit region =================
        for (int g = 0; g < ngroups; ++g) {
            const float s    = sh[((k0 >> 7) + g) * NFEAT + n];
            const float moff = -31.0f * s;
#pragma unroll
            for (int st = 0; st < 4; ++st) {
                const int k = k0 + g * 128 + st * 32 + kb;   // first of lane's 8 k
                const int G = k >> 2;                        // group-of-4 index
                const int* bp = Wh + 3 * G * NFEAT + n;
                const int b0 = bp[0];         const int b1 = bp[NFEAT];
                const int b2 = bp[2 * NFEAT]; const int b3 = bp[3 * NFEAT];
                const int b4 = bp[4 * NFEAT]; const int b5 = bp[5 * NFEAT];
                int v0 = b0 & 63;
                int v1 = ((b0 >> 6) & 3) | ((b1 & 15) << 2);
                int v2 = ((b1 >> 4) & 15) | ((b2 & 3) << 4);
                int v3 = (b2 >> 2) & 63;
                int v4 = b3 & 63;
                int v5 = ((b3 >> 6) & 3) | ((b4 & 15) << 2);
                int v6 = ((b4 >> 4) & 15) | ((b5 & 3) << 4);
                int v7 = (b5 >> 2) & 63;
                half8 b;
                b[0] = (_Float16)fmaf((float)v0, s, moff);
                b[1] = (_Float16)fmaf((float)v1, s, moff);
                b[2] = (_Float16)fmaf((float)v2, s, moff);
                b[3] = (_Float16)fmaf((float)v3, s, moff);
                b[4] = (_Float16)fmaf((float)v4, s, moff);
                b[5] = (_Float16)fmaf((float)v5, s, moff);
                b[6] = (_Float16)fmaf((float)v6, s, moff);
                b[7] = (_Float16)fmaf((float)v7, s, moff);
                const int sg = (k0 >> 5) + g * 4 + st;       // global 32-k step index
#pragma unroll
                for (int mt = 0; mt < 4; ++mt) {
                    half8 a = *(const half8*)(xfrag + (((sg * 4 + mt) * 64 + lane) << 3));
                    acc[mt] = __builtin_amdgcn_mfma_f32_16x16x32_f16(a, b, acc[mt], 0, 0, 0);
                }
            }
        }
    } else {
        // ================= 5-bit region =================
        const int kl0 = k0 - 1024;
        for (int g = 0; g < ngroups; ++g) {
            const float s    = sl[((kl0 >> 7) + g) * NFEAT + n];
            const float moff = -15.0f * s;
#pragma unroll
            for (int st = 0; st < 4; ++st) {
                const int kl = kl0 + g * 128 + st * 32 + kb; // first of lane's 8 k (low-rel)
                const int G8 = kl >> 3;                      // group-of-8 index
                const int* bp = Wl + 5 * G8 * NFEAT + n;
                const int b0 = bp[0];         const int b1 = bp[NFEAT];
                const int b2 = bp[2 * NFEAT]; const int b3 = bp[3 * NFEAT];
                const int b4 = bp[4 * NFEAT];
                int v0 = b0 & 31;
                int v1 = ((b0 >> 5) & 7) | ((b1 & 3) << 3);
                int v2 = (b1 >> 2) & 31;
                int v3 = ((b1 >> 7) & 1) | ((b2 & 15) << 1);
                int v4 = ((b2 >> 4) & 15) | ((b3 & 1) << 4);
                int v5 = (b3 >> 1) & 31;
                int v6 = ((b3 >> 6) & 3) | ((b4 & 7) << 2);
                int v7 = (b4 >> 3) & 31;
                half8 b;
                b[0] = (_Float16)fmaf((float)v0, s, moff);
                b[1] = (_Float16)fmaf((float)v1, s, moff);
                b[2] = (_Float16)fmaf((float)v2, s, moff);
                b[3] = (_Float16)fmaf((float)v3, s, moff);
                b[4] = (_Float16)fmaf((float)v4, s, moff);
                b[5] = (_Float16)fmaf((float)v5, s, moff);
                b[6] = (_Float16)fmaf((float)v6, s, moff);
                b[7] = (_Float16)fmaf((float)v7, s, moff);
                const int sg = 32 + (kl0 >> 5) + g * 4 + st; // global step (k0 = kl0+1024)
#pragma unroll
                for (int mt = 0; mt < 4; ++mt) {
                    half8 a = *(const half8*)(xfrag + (((sg * 4 + mt) * 64 + lane) << 3));
                    acc[mt] = __builtin_amdgcn_mfma_f32_16x16x32_f16(a, b, acc[mt], 0, 0, 0);
                }
            }
        }
    }

    // ---- epilogue: D row = mt*16 + (lane>>4)*4 + r, col = n ----
    const int r0 = (lane >> 4) << 2;
    if (atomic_mode) {
#pragma unroll
        for (int mt = 0; mt < 4; ++mt)
#pragma unroll
            for (int r = 0; r < 4; ++r)
                atomicAdd(&dst[(mt * 16 + r0 + r) * NFEAT + n], acc[mt][r]);
    } else {
        float* base = dst + (size_t)kc * 64 * NFEAT;
#pragma unroll
        for (int mt = 0; mt < 4; ++mt)
#pragma unroll
            for (int r = 0; r < 4; ++r)
                base[(mt * 16 + r0 + r) * NFEAT + n] = acc[mt][r];
    }
}

// ---------------- reduce: out = bias + sum_kc partial[kc] ----------------
__global__ __launch_bounds__(256) void reduce_out(const float* __restrict__ part,
                                                  const float* __restrict__ bias,
                                                  float* __restrict__ out, int nc) {
    const int idx = blockIdx.x * 256 + threadIdx.x;    // 0..176127 (float4 units)
    const int f   = idx * 4;
    const int n   = f % NFEAT;                          // NFEAT % 4 == 0 -> same row
    f32x4 sum = *(const f32x4*)(bias + n);
    for (int c = 0; c < nc; ++c)
        sum += *(const f32x4*)(part + (size_t)c * 704512 + f);
    *(f32x4*)(out + f) = sum;
}

__global__ __launch_bounds__(256) void init_bias(const float* __restrict__ bias,
                                                 float* __restrict__ out) {
    const int idx = blockIdx.x * 256 + threadIdx.x;    // 0..704511
    out[idx] = bias[idx % NFEAT];
}

extern "C" void kernel_launch(void* const* d_in, const int* in_sizes, int n_in,
                              void* d_out, int out_size, void* d_ws, size_t ws_size,
                              hipStream_t stream) {
    const float* x    = (const float*)d_in[0];
    const int*   Wh   = (const int*)d_in[1];
    const int*   Wl   = (const int*)d_in[2];
    const float* sh   = (const float*)d_in[3];
    const float* sl   = (const float*)d_in[4];
    const int*   col  = (const int*)d_in[5];
    const float* bias = (const float*)d_in[6];
    float* out = (float*)d_out;

    _Float16* xfrag = (_Float16*)d_ws;                 // 512 KB
    const size_t xfrag_bytes = 64 * KTOT * sizeof(_Float16);
    const size_t part1 = 64ull * NFEAT * sizeof(float);         // 2.816 MB per chunk

    prep_xfrag<<<1024, 256, 0, stream>>>(x, col, xfrag);

    if (ws_size >= xfrag_bytes + 8 * part1) {
        float* part = (float*)((char*)d_ws + xfrag_bytes);
        gemm_kernel<<<dim3(172, 8), 256, 0, stream>>>(Wh, Wl, sh, sl, xfrag, part, 0);
        reduce_out<<<688, 256, 0, stream>>>(part, bias, out, 8);
    } else if (ws_size >= xfrag_bytes + 4 * part1) {
        float* part = (float*)((char*)d_ws + xfrag_bytes);
        gemm_kernel<<<dim3(172, 4), 256, 0, stream>>>(Wh, Wl, sh, sl, xfrag, part, 0);
        reduce_out<<<688, 256, 0, stream>>>(part, bias, out, 4);
    } else {
        init_bias<<<2752, 256, 0, stream>>>(bias, out);
        gemm_kernel<<<dim3(172, 8), 256, 0, stream>>>(Wh, Wl, sh, sl, xfrag, out, 1);
    }
}

// Round 5
// 173.019 us; speedup vs baseline: 1.1173x; 1.1173x over previous
//
#include <hip/hip_runtime.h>

// CPRPackedLinear: out(64x11008) = xperm[:, :1024] @ deq6(W_high) + xperm[:, 1024:] @ deq5(W_low) + bias
//
// R5: all four prior schedules staged weights through VGPRs -> compiler
// register-minimizes (VGPR 32-48) and serializes load->dequant->MFMA; every
// variant pinned at ~2 TB/s effective. This version uses the guide's proven
// fast path: __builtin_amdgcn_global_load_lds staging (zero register cost per
// in-flight load) + 4-buffer rotation + counted s_waitcnt vmcnt(14/12) that is
// never drained to 0 in the main loop (T3+T4), raw s_barrier per step.
// Waves own disjoint 16-col strips (no epilogue reduce). Depth-2 prefetch:
// ~5KB in flight per wave, ~61KB/CU at 12 waves/CU >> BW*latency (~15KB).

#define NFEAT 11008
#define KTOT  4096

typedef _Float16 half8 __attribute__((ext_vector_type(8)));
typedef float    f32x4 __attribute__((ext_vector_type(4)));

#define GLOAD4(g, l)  __builtin_amdgcn_global_load_lds(                         \
    (const __attribute__((address_space(1))) unsigned int*)(g),                 \
    (__attribute__((address_space(3))) unsigned int*)(l), 4, 0, 0)
#define GLOAD16(g, l) __builtin_amdgcn_global_load_lds(                         \
    (const __attribute__((address_space(1))) unsigned int*)(g),                 \
    (__attribute__((address_space(3))) unsigned int*)(l), 16, 0, 0)
#define WAITV(N) asm volatile("s_waitcnt vmcnt(" #N ")" ::: "memory")

// ---------------- prep: x_perm -> fp16 in MFMA A-fragment layout ----------------
// xfrag flat idx = ((s*4 + mt)*64 + lane)*8 + j
//   holds x[m = mt*16 + (lane&15)][ col_indices[k = s*32 + (lane>>4)*8 + j] ]
__global__ __launch_bounds__(256) void prep_xfrag(const float* __restrict__ x,
                                                  const int* __restrict__ col,
                                                  _Float16* __restrict__ xfrag) {
    int idx = blockIdx.x * 256 + threadIdx.x;          // 0..262143
    int j  = idx & 7;
    int l  = (idx >> 3) & 63;
    int mt = (idx >> 9) & 3;
    int s  = idx >> 11;
    int k  = s * 32 + ((l >> 4) << 3) + j;
    int m  = mt * 16 + (l & 15);
    xfrag[idx] = (_Float16)x[m * KTOT + col[k]];
}

// ---------------- main GEMM ----------------
// grid = (172, 4): 64-col tiles x 1024-k chunks (kc0 = 6-bit, kc1..3 = 5-bit).
// block = 256 = 4 waves. Wave w owns cols [n0+16w, n0+16w+16), rows 0..63.
// Per 32-k step: stage 24 (6b) / 20 (5b) packed rows + 4 A-frags into LDS via
// global_load_lds; each lane dequants its k-octet straight into the MFMA B-frag.
__global__ __launch_bounds__(256, 3) void gemm_kernel(const int* __restrict__ Wh,
                                                      const int* __restrict__ Wl,
                                                      const float* __restrict__ sh,
                                                      const float* __restrict__ sl,
                                                      const _Float16* __restrict__ xfrag,
                                                      float* __restrict__ dst,
                                                      int atomic_mode) {
    const int n0   = blockIdx.x * 64;
    const int kc   = blockIdx.y;
    const int lane = threadIdx.x & 63;
    const int wave = threadIdx.x >> 6;                  // 0..3
    const int cb   = wave * 16 + (lane & 15);           // block-local col 0..63
    const int n    = n0 + cb;                           // global output column
    const int o    = lane >> 4;                         // k-octet 0..3

    // W rows: stride 68 ints (6-bit, 24 rows) or 72 ints (5-bit, 20 rows);
    // 16B/32B pad rotates banks so the 4 octet-groups' reads are <=2-way.
    __shared__ int Wb[4][1632];                         // 4 bufs x 6528 B
    __shared__ __align__(16) _Float16 Ab[4][4][512];    // 4 bufs x 4 mt x 1 KB

    f32x4 acc[4];
#pragma unroll
    for (int i = 0; i < 4; ++i) acc[i] = (f32x4){0.f, 0.f, 0.f, 0.f};

    if (kc == 0) {
        // ================= 6-bit region (k 0..1024, 32 steps) =================
        float sc[8];
#pragma unroll
        for (int g = 0; g < 8; ++g) sc[g] = sh[g * NFEAT + n];   // statically indexed

#define STAGE6(T) do {                                                         \
        const int _t = (T); const int _b = _t & 3;                             \
        const int* _gs = Wh + (_t * 24 + wave * 6) * NFEAT + n0 + lane;        \
        GLOAD4(_gs,             &Wb[_b][(wave * 6 + 0) * 68]);                 \
        GLOAD4(_gs + 1 * NFEAT, &Wb[_b][(wave * 6 + 1) * 68]);                 \
        GLOAD4(_gs + 2 * NFEAT, &Wb[_b][(wave * 6 + 2) * 68]);                 \
        GLOAD4(_gs + 3 * NFEAT, &Wb[_b][(wave * 6 + 3) * 68]);                 \
        GLOAD4(_gs + 4 * NFEAT, &Wb[_b][(wave * 6 + 4) * 68]);                 \
        GLOAD4(_gs + 5 * NFEAT, &Wb[_b][(wave * 6 + 5) * 68]);                 \
        GLOAD16(xfrag + ((size_t)(_t * 4 + wave) * 64 + lane) * 8,             \
                &Ab[_b][wave][0]);                                             \
    } while (0)

        STAGE6(0);
        STAGE6(1);
#pragma unroll
        for (int g = 0; g < 8; ++g) {
            for (int st = 0; st < 4; ++st) {
                const int t = g * 4 + st;
                if (t + 2 < 32) { STAGE6(t + 2); WAITV(14); }   // 2 batches x 7 in flight
                else if (t + 1 < 32) { WAITV(7); }
                else { WAITV(0); }
                __builtin_amdgcn_s_barrier();
                asm volatile("" ::: "memory");

                const int  bi = t & 3;
                const int* wr = &Wb[bi][(o * 6) * 68 + cb];
                const int b0 = wr[0];      const int b1 = wr[68];
                const int b2 = wr[2 * 68]; const int b3 = wr[3 * 68];
                const int b4 = wr[4 * 68]; const int b5 = wr[5 * 68];
                int v0 = b0 & 63;
                int v1 = ((b0 >> 6) & 3) | ((b1 & 15) << 2);
                int v2 = ((b1 >> 4) & 15) | ((b2 & 3) << 4);
                int v3 = (b2 >> 2) & 63;
                int v4 = b3 & 63;
                int v5 = ((b3 >> 6) & 3) | ((b4 & 15) << 2);
                int v6 = ((b4 >> 4) & 15) | ((b5 & 3) << 4);
                int v7 = (b5 >> 2) & 63;
                const float s = sc[g], moff = -31.0f * sc[g];
                half8 bf;
                bf[0] = (_Float16)fmaf((float)v0, s, moff);
                bf[1] = (_Float16)fmaf((float)v1, s, moff);
                bf[2] = (_Float16)fmaf((float)v2, s, moff);
                bf[3] = (_Float16)fmaf((float)v3, s, moff);
                bf[4] = (_Float16)fmaf((float)v4, s, moff);
                bf[5] = (_Float16)fmaf((float)v5, s, moff);
                bf[6] = (_Float16)fmaf((float)v6, s, moff);
                bf[7] = (_Float16)fmaf((float)v7, s, moff);
#pragma unroll
                for (int mt = 0; mt < 4; ++mt) {
                    half8 a = *(const half8*)&Ab[bi][mt][lane * 8];
                    acc[mt] = __builtin_amdgcn_mfma_f32_16x16x32_f16(a, bf, acc[mt], 0, 0, 0);
                }
            }
        }
#undef STAGE6
    } else {
        // ================= 5-bit region (chunk kc: k 1024*kc..+1024) =================
        const int klc   = kc - 1;                       // 0..2
        const int rbase = klc * 640;                    // packed-row base in Wl
        float sc[8];
#pragma unroll
        for (int g = 0; g < 8; ++g) sc[g] = sl[(klc * 8 + g) * NFEAT + n];

#define STAGE5(T) do {                                                         \
        const int _t = (T); const int _b = _t & 3;                             \
        const int* _gs = Wl + (rbase + _t * 20 + wave * 5) * NFEAT + n0 + lane;\
        GLOAD4(_gs,             &Wb[_b][(wave * 5 + 0) * 72]);                 \
        GLOAD4(_gs + 1 * NFEAT, &Wb[_b][(wave * 5 + 1) * 72]);                 \
        GLOAD4(_gs + 2 * NFEAT, &Wb[_b][(wave * 5 + 2) * 72]);                 \
        GLOAD4(_gs + 3 * NFEAT, &Wb[_b][(wave * 5 + 3) * 72]);                 \
        GLOAD4(_gs + 4 * NFEAT, &Wb[_b][(wave * 5 + 4) * 72]);                 \
        GLOAD16(xfrag + ((size_t)((kc * 32 + _t) * 4 + wave) * 64 + lane) * 8, \
                &Ab[_b][wave][0]);                                             \
    } while (0)

        STAGE5(0);
        STAGE5(1);
#pragma unroll
        for (int g = 0; g < 8; ++g) {
            for (int st = 0; st < 4; ++st) {
                const int t = g * 4 + st;
                if (t + 2 < 32) { STAGE5(t + 2); WAITV(12); }   // 2 batches x 6 in flight
                else if (t + 1 < 32) { WAITV(6); }
                else { WAITV(0); }
                __builtin_amdgcn_s_barrier();
                asm volatile("" ::: "memory");

                const int  bi = t & 3;
                const int* wr = &Wb[bi][(o * 5) * 72 + cb];
                const int b0 = wr[0];      const int b1 = wr[72];
                const int b2 = wr[2 * 72]; const int b3 = wr[3 * 72];
                const int b4 = wr[4 * 72];
                int v0 = b0 & 31;
                int v1 = ((b0 >> 5) & 7) | ((b1 & 3) << 3);
                int v2 = (b1 >> 2) & 31;
                int v3 = ((b1 >> 7) & 1) | ((b2 & 15) << 1);
                int v4 = ((b2 >> 4) & 15) | ((b3 & 1) << 4);
                int v5 = (b3 >> 1) & 31;
                int v6 = ((b3 >> 6) & 3) | ((b4 & 7) << 2);
                int v7 = (b4 >> 3) & 31;
                const float s = sc[g], moff = -15.0f * sc[g];
                half8 bf;
                bf[0] = (_Float16)fmaf((float)v0, s, moff);
                bf[1] = (_Float16)fmaf((float)v1, s, moff);
                bf[2] = (_Float16)fmaf((float)v2, s, moff);
                bf[3] = (_Float16)fmaf((float)v3, s, moff);
                bf[4] = (_Float16)fmaf((float)v4, s, moff);
                bf[5] = (_Float16)fmaf((float)v5, s, moff);
                bf[6] = (_Float16)fmaf((float)v6, s, moff);
                bf[7] = (_Float16)fmaf((float)v7, s, moff);
#pragma unroll
                for (int mt = 0; mt < 4; ++mt) {
                    half8 a = *(const half8*)&Ab[bi][mt][lane * 8];
                    acc[mt] = __builtin_amdgcn_mfma_f32_16x16x32_f16(a, bf, acc[mt], 0, 0, 0);
                }
            }
        }
#undef STAGE5
    }

    // ---- epilogue: waves own disjoint cols -> direct store ----
    // D row = mt*16 + (lane>>4)*4 + r, col = n
    const int r0 = (lane >> 4) << 2;
    if (atomic_mode) {
#pragma unroll
        for (int mt = 0; mt < 4; ++mt)
#pragma unroll
            for (int r = 0; r < 4; ++r)
                atomicAdd(&dst[(mt * 16 + r0 + r) * NFEAT + n], acc[mt][r]);
    } else {
        float* base = dst + (size_t)kc * 64 * NFEAT;
#pragma unroll
        for (int mt = 0; mt < 4; ++mt)
#pragma unroll
            for (int r = 0; r < 4; ++r)
                base[(mt * 16 + r0 + r) * NFEAT + n] = acc[mt][r];
    }
}

// ---------------- reduce: out = bias + sum_kc partial[kc] ----------------
__global__ __launch_bounds__(256) void reduce_out(const float* __restrict__ part,
                                                  const float* __restrict__ bias,
                                                  float* __restrict__ out, int nc) {
    const int idx = blockIdx.x * 256 + threadIdx.x;    // 0..176127 (float4 units)
    const int f   = idx * 4;
    const int n   = f % NFEAT;                          // NFEAT % 4 == 0 -> same row
    f32x4 sum = *(const f32x4*)(bias + n);
    for (int c = 0; c < nc; ++c)
        sum += *(const f32x4*)(part + (size_t)c * 704512 + f);
    *(f32x4*)(out + f) = sum;
}

__global__ __launch_bounds__(256) void init_bias(const float* __restrict__ bias,
                                                 float* __restrict__ out) {
    const int idx = blockIdx.x * 256 + threadIdx.x;    // 0..704511
    out[idx] = bias[idx % NFEAT];
}

extern "C" void kernel_launch(void* const* d_in, const int* in_sizes, int n_in,
                              void* d_out, int out_size, void* d_ws, size_t ws_size,
                              hipStream_t stream) {
    const float* x    = (const float*)d_in[0];
    const int*   Wh   = (const int*)d_in[1];
    const int*   Wl   = (const int*)d_in[2];
    const float* sh   = (const float*)d_in[3];
    const float* sl   = (const float*)d_in[4];
    const int*   col  = (const int*)d_in[5];
    const float* bias = (const float*)d_in[6];
    float* out = (float*)d_out;

    _Float16* xfrag = (_Float16*)d_ws;                 // 512 KB
    const size_t xfrag_bytes = 64 * KTOT * sizeof(_Float16);
    const size_t part1 = 64ull * NFEAT * sizeof(float);         // 2.816 MB per chunk

    prep_xfrag<<<1024, 256, 0, stream>>>(x, col, xfrag);

    dim3 grid(172, 4);
    if (ws_size >= xfrag_bytes + 4 * part1) {
        float* part = (float*)((char*)d_ws + xfrag_bytes);
        gemm_kernel<<<grid, 256, 0, stream>>>(Wh, Wl, sh, sl, xfrag, part, 0);
        reduce_out<<<688, 256, 0, stream>>>(part, bias, out, 4);
    } else {
        init_bias<<<2752, 256, 0, stream>>>(bias, out);
        gemm_kernel<<<grid, 256, 0, stream>>>(Wh, Wl, sh, sl, xfrag, out, 1);
    }
}